// Round 20
// baseline (535.656 us; speedup 1.0000x reference)
//
#include <hip/hip_runtime.h>
#include <hip/hip_bf16.h>
#include <cstdint>

#define QMAXF 127.0f
#define EPSQ 1e-8f

typedef __bf16 bf16x8 __attribute__((ext_vector_type(8)));
typedef float f32x4 __attribute__((ext_vector_type(4)));

static constexpr int BB = 32;   // 2*16 batch
static constexpr int MM = 2048;
static constexpr int KK = 128;
static constexpr int NN = 2048;

// workspace layout (bytes)
static constexpr size_t OFF_Q1   = 0;                                  // ushort tile-images of A (swizzled)
static constexpr size_t OFF_Q2T  = OFF_Q1  + (size_t)BB*MM*KK*2;       // ushort tile-images of B^T (swizzled)
static constexpr size_t OFF_S1   = OFF_Q2T + (size_t)BB*NN*KK*2;       // float[B*M]
static constexpr size_t OFF_S2   = OFF_S1  + (size_t)BB*MM*4;          // float[B*K]

// ---------------- quantize inputs1: per-row (K=128) amax; store exact-int bf16, K-swizzled ----------------
__global__ __launch_bounds__(256) void quant_rows128(const float* __restrict__ x,
                                                     unsigned short* __restrict__ q,
                                                     float* __restrict__ s1) {
    int wave = threadIdx.x >> 6, lane = threadIdx.x & 63;
    int row = blockIdx.x * 4 + wave;               // 65536 rows
    const float2* xr = reinterpret_cast<const float2*>(x) + (size_t)row * 64;
    float2 v = xr[lane];
    float a = fmaxf(fabsf(v.x), fabsf(v.y));
#pragma unroll
    for (int m = 32; m; m >>= 1) a = fmaxf(a, __shfl_xor(a, m));
    float scale = fmaxf(a, EPSQ) / QMAXF;
    float i0 = fminf(fmaxf(rintf(v.x / scale), -128.f), 127.f);
    float i1 = fminf(fmaxf(rintf(v.y / scale), -128.f), 127.f);
    __bf16 h0 = (__bf16)i0, h1 = (__bf16)i1;       // integers <=128: exact in bf16
    ushort2 st;
    st.x = *reinterpret_cast<unsigned short*>(&h0);
    st.y = *reinterpret_cast<unsigned short*>(&h1);
    // swizzle: ushort idx (2*lane) ^ ((row&7)<<3)  ->  ushort2 idx lane ^ ((row&7)<<2)
    reinterpret_cast<ushort2*>(q + (size_t)row * 128)[lane ^ ((row & 7) << 2)] = st;
    if (lane == 0) s1[row] = scale;
}

// ---------------- inputs2: per-k-row (N=2048) amax -> s2 ----------------
__global__ __launch_bounds__(256) void amax_rows2048(const float* __restrict__ x,
                                                     float* __restrict__ s2) {
    int row = blockIdx.x;                          // B*K = 4096 rows
    const float4* xr = reinterpret_cast<const float4*>(x) + (size_t)row * 512;
    int t = threadIdx.x;
    float4 v0 = xr[t], v1 = xr[t + 256];
    float a = fmaxf(fmaxf(fmaxf(fabsf(v0.x), fabsf(v0.y)), fmaxf(fabsf(v0.z), fabsf(v0.w))),
                    fmaxf(fmaxf(fabsf(v1.x), fabsf(v1.y)), fmaxf(fabsf(v1.z), fabsf(v1.w))));
#pragma unroll
    for (int m = 32; m; m >>= 1) a = fmaxf(a, __shfl_xor(a, m));
    __shared__ float red[4];
    if ((t & 63) == 0) red[t >> 6] = a;
    __syncthreads();
    if (t == 0) {
        float m0 = fmaxf(fmaxf(red[0], red[1]), fmaxf(red[2], red[3]));
        s2[row] = fmaxf(m0, EPSQ) / QMAXF;
    }
}

// ---------------- inputs2: dequantize + transpose to q2t image [b*16+nt][rn][k^swz] ----------------
__global__ __launch_bounds__(256) void quant_transpose(const float* __restrict__ x,
                                                       const float* __restrict__ s2,
                                                       unsigned short* __restrict__ q2t) {
    int b = blockIdx.x >> 5;
    int n0 = (blockIdx.x & 31) * 64;
    __shared__ unsigned short lds[64][136];
    int t = threadIdx.x;
    int rr = t >> 4, cc = t & 15;
#pragma unroll
    for (int p = 0; p < 8; ++p) {
        int k = p * 16 + rr;
        float s = s2[b * 128 + k];
        const float4* src = reinterpret_cast<const float4*>(x + ((size_t)b * 128 + k) * 2048 + n0);
        float4 v = src[cc];
        float f[4] = {v.x, v.y, v.z, v.w};
#pragma unroll
        for (int e = 0; e < 4; ++e) {
            float iq = fminf(fmaxf(rintf(f[e] / s), -128.f), 127.f);
            __bf16 h = (__bf16)(iq * s);
            lds[cc * 4 + e][k] = *reinterpret_cast<unsigned short*>(&h);
        }
    }
    __syncthreads();
    int nl = t >> 2, seg = t & 3;
    int sw = nl & 7;                               // (n0+nl)&7 == nl&7 (n0 multiple of 64)
    uint4* dstrow = reinterpret_cast<uint4*>(q2t + ((size_t)b * 2048 + n0 + nl) * 128);
#pragma unroll
    for (int j = 0; j < 4; ++j)
        dstrow[(seg * 4 + j) ^ sw] = *reinterpret_cast<const uint4*>(&lds[nl][seg * 32 + j * 8]);
}

// ---------------- fused GEMM: one block per (b, mt) 128x2048 row-panel. NO LDS staging.
// TALL-NARROW wave tile (128 rows x 16 cols) + DEPTH-4 rolling B banks:
// MFMA(t) waits loads issued at t-4, so 4 iterations of stores (32 KB/wave, 256 KB/CU)
// stay in flight -> write stream saturates HBM instead of serializing on store-ack
// (in-order vmcnt, m135; R16 depth-1 measured 3.9 TB/s by Little's law). ----------------
__global__ __launch_bounds__(256, 2) void gemm_fused(const unsigned short* __restrict__ qa,
                                                     const unsigned short* __restrict__ qbt,
                                                     const float* __restrict__ s1,
                                                     float* __restrict__ out) {
    int id = blockIdx.x;
    int nid = (id & 7) * 64 + (id >> 3);           // batch-grouped XCD mapping (512 % 8 == 0)
    int b = nid >> 4, mt = nid & 15;

    __shared__ float rowAmax[128], sS1[128];
    __shared__ float2 sQO[128];                    // (qs, osc) per row — one ds_read_b64

    int tid = threadIdx.x, wave = tid >> 6, lane = tid & 63;
    if (tid < 128) {
        rowAmax[tid] = 0.f;
        sS1[tid] = s1[b * 2048 + mt * 128 + tid];
    }
    __syncthreads();                               // zeroing visible before any atomicMax

    int lr = lane & 15, lg = lane >> 4;
    int swz = (lr & 7) << 3;                       // XOR swizzle baked into the images

    // A fragments: whole 128-row panel per wave (loaded once, L2/L3-hot). 128 VGPR.
    bf16x8 afr[4][8];                              // [ks][mi], rows mi*16+lr
    {
        const unsigned short* Ai = qa + (size_t)(b * 16 + mt) * 16384;
#pragma unroll
        for (int ks = 0; ks < 4; ++ks)
#pragma unroll
            for (int mi = 0; mi < 8; ++mi)
                afr[ks][mi] = *reinterpret_cast<const bf16x8*>(
                    &Ai[(mi * 16 + lr) * 128 + ((ks * 32 + lg * 8) ^ swz)]);
    }

    const unsigned short* Bimg = qbt + (size_t)b * 16 * 16384;
    // 32 column-tiles of 64; wave owns 16-col slice [wave*16, wave*16+16)
    auto boff = [&](int t64, int ks) -> size_t {
        return (size_t)(t64 * 64 + wave * 16 + lr) * 128 + ((ks * 32 + lg * 8) ^ swz);
    };

    // depth-4 rolling banks (named: static indexing per rule #20)
    bf16x8 bk0[4], bk1[4], bk2[4], bk3[4];
#pragma unroll
    for (int ks = 0; ks < 4; ++ks) {
        bk0[ks] = *reinterpret_cast<const bf16x8*>(&Bimg[boff(0, ks)]);
        bk1[ks] = *reinterpret_cast<const bf16x8*>(&Bimg[boff(1, ks)]);
        bk2[ks] = *reinterpret_cast<const bf16x8*>(&Bimg[boff(2, ks)]);
        bk3[ks] = *reinterpret_cast<const bf16x8*>(&Bimg[boff(3, ks)]);
    }

    size_t ob = (size_t)b * 2048 * 2048;
    float rmax[8];
#pragma unroll
    for (int mi = 0; mi < 8; ++mi) rmax[mi] = 0.f;

    // ---- sweep 1: amax; MFMA + per-lane running max; refill bank with tile t+4 ----
    auto s1body = [&](int t, bf16x8 (&bank)[4]) {
        f32x4 acc[8];
#pragma unroll
        for (int mi = 0; mi < 8; ++mi) { f32x4 z = {0.f,0.f,0.f,0.f}; acc[mi] = z; }
        int nn = (t + 4) & 31;
#pragma unroll
        for (int ks = 0; ks < 4; ++ks) {
            // SWAPPED operands (R10/R12-verified): lane holds row=lr, cols=lg*4+r
#pragma unroll
            for (int mi = 0; mi < 8; ++mi)
                acc[mi] = __builtin_amdgcn_mfma_f32_16x16x32_bf16(bank[ks], afr[ks][mi], acc[mi], 0, 0, 0);
            bank[ks] = *reinterpret_cast<const bf16x8*>(&Bimg[boff(nn, ks)]);
        }
#pragma unroll
        for (int mi = 0; mi < 8; ++mi)
#pragma unroll
            for (int r = 0; r < 4; ++r)
                rmax[mi] = fmaxf(rmax[mi], fabsf(acc[mi][r]));
    };
    for (int t = 0; t < 32; t += 4) {
        s1body(t + 0, bk0);
        s1body(t + 1, bk1);
        s1body(t + 2, bk2);
        s1body(t + 3, bk3);
    }

    // ---- boundary: reduce amax -> per-row (qs, osc) ----
#pragma unroll
    for (int mi = 0; mi < 8; ++mi) {
        float v = rmax[mi];
        v = fmaxf(v, __shfl_xor(v, 16));
        v = fmaxf(v, __shfl_xor(v, 32));
        if (lg == 0) {                             // raw amax >=0: uint compare == float compare
            atomicMax(reinterpret_cast<unsigned*>(&rowAmax[mi * 16 + lr]), __float_as_uint(v));
        }
    }
    __syncthreads();
    if (tid < 128) {
        float am = rowAmax[tid] * sS1[tid];
        float osc = fmaxf(am, EPSQ) / QMAXF;
        sQO[tid] = make_float2(sS1[tid] / osc, osc);   // folded (raw*s1)/osc, osc
    }
    __syncthreads();                               // banks hold tiles 0..3 again (wrapped)

    // ---- sweep 2: quantize + store; 4 iterations of stores stay outstanding ----
    auto s2body = [&](int t, bf16x8 (&bank)[4]) {
        f32x4 acc[8];
#pragma unroll
        for (int mi = 0; mi < 8; ++mi) { f32x4 z = {0.f,0.f,0.f,0.f}; acc[mi] = z; }
        int nn = (t + 4) & 31;
#pragma unroll
        for (int ks = 0; ks < 4; ++ks) {
#pragma unroll
            for (int mi = 0; mi < 8; ++mi)
                acc[mi] = __builtin_amdgcn_mfma_f32_16x16x32_bf16(bank[ks], afr[ks][mi], acc[mi], 0, 0, 0);
            bank[ks] = *reinterpret_cast<const bf16x8*>(&Bimg[boff(nn, ks)]);
        }
        // stores YOUNGER than the 4-ahead loads -> MFMA waits never drain the last 4 iters of stores
#pragma unroll
        for (int mi = 0; mi < 8; ++mi) {
            int row = mi * 16 + lr;
            float2 qo = sQO[row];
            f32x4 qv;
            qv[0] = fminf(fmaxf(rintf(acc[mi][0] * qo.x), -128.f), 127.f) * qo.y;
            qv[1] = fminf(fmaxf(rintf(acc[mi][1] * qo.x), -128.f), 127.f) * qo.y;
            qv[2] = fminf(fmaxf(rintf(acc[mi][2] * qo.x), -128.f), 127.f) * qo.y;
            qv[3] = fminf(fmaxf(rintf(acc[mi][3] * qo.x), -128.f), 127.f) * qo.y;
            *reinterpret_cast<f32x4*>(
                &out[ob + (size_t)(mt * 128 + row) * 2048 + t * 64 + wave * 16 + lg * 4]) = qv;
        }
    };
    for (int t = 0; t < 32; t += 4) {
        s2body(t + 0, bk0);
        s2body(t + 1, bk1);
        s2body(t + 2, bk2);
        s2body(t + 3, bk3);
    }
}

extern "C" void kernel_launch(void* const* d_in, const int* in_sizes, int n_in,
                              void* d_out, int out_size, void* d_ws, size_t ws_size,
                              hipStream_t stream) {
    const float* in1 = (const float*)d_in[0];  // [2,16,2048,128]
    const float* in2 = (const float*)d_in[1];  // [2,16,128,2048]
    char* ws = (char*)d_ws;
    unsigned short* q1  = (unsigned short*)(ws + OFF_Q1);
    unsigned short* q2t = (unsigned short*)(ws + OFF_Q2T);
    float* s1   = (float*)(ws + OFF_S1);
    float* s2   = (float*)(ws + OFF_S2);
    float* out  = (float*)d_out;

    quant_rows128 <<<BB * MM / 4, 256, 0, stream>>>(in1, q1, s1);
    amax_rows2048 <<<BB * KK,     256, 0, stream>>>(in2, s2);
    quant_transpose<<<BB * (NN / 64), 256, 0, stream>>>(in2, s2, q2t);
    gemm_fused    <<<BB * 16,     256, 0, stream>>>(q1, q2t, s1, out);
}

// Round 21
// 259.358 us; speedup vs baseline: 2.0653x; 2.0653x over previous
//
#include <hip/hip_runtime.h>
#include <hip/hip_bf16.h>
#include <cstdint>

#define QMAXF 127.0f
#define EPSQ 1e-8f

typedef __bf16 bf16x8 __attribute__((ext_vector_type(8)));
typedef float f32x4 __attribute__((ext_vector_type(4)));

static constexpr int BB = 32;   // 2*16 batch
static constexpr int MM = 2048;
static constexpr int KK = 128;
static constexpr int NN = 2048;

// workspace layout (bytes)
static constexpr size_t OFF_Q1   = 0;                                  // ushort tile-images of A (swizzled)
static constexpr size_t OFF_Q2T  = OFF_Q1  + (size_t)BB*MM*KK*2;       // ushort tile-images of B^T (swizzled)
static constexpr size_t OFF_S1   = OFF_Q2T + (size_t)BB*NN*KK*2;       // float[B*M]
static constexpr size_t OFF_S2   = OFF_S1  + (size_t)BB*MM*4;          // float[B*K]

// ---------------- quantize inputs1: per-row (K=128) amax; store exact-int bf16, K-swizzled ----------------
__global__ __launch_bounds__(256) void quant_rows128(const float* __restrict__ x,
                                                     unsigned short* __restrict__ q,
                                                     float* __restrict__ s1) {
    int wave = threadIdx.x >> 6, lane = threadIdx.x & 63;
    int row = blockIdx.x * 4 + wave;               // 65536 rows
    const float2* xr = reinterpret_cast<const float2*>(x) + (size_t)row * 64;
    float2 v = xr[lane];
    float a = fmaxf(fabsf(v.x), fabsf(v.y));
#pragma unroll
    for (int m = 32; m; m >>= 1) a = fmaxf(a, __shfl_xor(a, m));
    float scale = fmaxf(a, EPSQ) / QMAXF;
    float i0 = fminf(fmaxf(rintf(v.x / scale), -128.f), 127.f);
    float i1 = fminf(fmaxf(rintf(v.y / scale), -128.f), 127.f);
    __bf16 h0 = (__bf16)i0, h1 = (__bf16)i1;       // integers <=128: exact in bf16
    ushort2 st;
    st.x = *reinterpret_cast<unsigned short*>(&h0);
    st.y = *reinterpret_cast<unsigned short*>(&h1);
    // swizzle: ushort idx (2*lane) ^ ((row&7)<<3)  ->  ushort2 idx lane ^ ((row&7)<<2)
    reinterpret_cast<ushort2*>(q + (size_t)row * 128)[lane ^ ((row & 7) << 2)] = st;
    if (lane == 0) s1[row] = scale;
}

// ---------------- inputs2: per-k-row (N=2048) amax -> s2 ----------------
__global__ __launch_bounds__(256) void amax_rows2048(const float* __restrict__ x,
                                                     float* __restrict__ s2) {
    int row = blockIdx.x;                          // B*K = 4096 rows
    const float4* xr = reinterpret_cast<const float4*>(x) + (size_t)row * 512;
    int t = threadIdx.x;
    float4 v0 = xr[t], v1 = xr[t + 256];
    float a = fmaxf(fmaxf(fmaxf(fabsf(v0.x), fabsf(v0.y)), fmaxf(fabsf(v0.z), fabsf(v0.w))),
                    fmaxf(fmaxf(fabsf(v1.x), fabsf(v1.y)), fmaxf(fabsf(v1.z), fabsf(v1.w))));
#pragma unroll
    for (int m = 32; m; m >>= 1) a = fmaxf(a, __shfl_xor(a, m));
    __shared__ float red[4];
    if ((t & 63) == 0) red[t >> 6] = a;
    __syncthreads();
    if (t == 0) {
        float m0 = fmaxf(fmaxf(red[0], red[1]), fmaxf(red[2], red[3]));
        s2[row] = fmaxf(m0, EPSQ) / QMAXF;
    }
}

// ---------------- inputs2: dequantize + transpose to q2t image [b*16+nt][rn][k^swz] ----------------
__global__ __launch_bounds__(256) void quant_transpose(const float* __restrict__ x,
                                                       const float* __restrict__ s2,
                                                       unsigned short* __restrict__ q2t) {
    int b = blockIdx.x >> 5;
    int n0 = (blockIdx.x & 31) * 64;
    __shared__ unsigned short lds[64][136];
    int t = threadIdx.x;
    int rr = t >> 4, cc = t & 15;
#pragma unroll
    for (int p = 0; p < 8; ++p) {
        int k = p * 16 + rr;
        float s = s2[b * 128 + k];
        const float4* src = reinterpret_cast<const float4*>(x + ((size_t)b * 128 + k) * 2048 + n0);
        float4 v = src[cc];
        float f[4] = {v.x, v.y, v.z, v.w};
#pragma unroll
        for (int e = 0; e < 4; ++e) {
            float iq = fminf(fmaxf(rintf(f[e] / s), -128.f), 127.f);
            __bf16 h = (__bf16)(iq * s);
            lds[cc * 4 + e][k] = *reinterpret_cast<unsigned short*>(&h);
        }
    }
    __syncthreads();
    int nl = t >> 2, seg = t & 3;
    int sw = nl & 7;                               // (n0+nl)&7 == nl&7 (n0 multiple of 64)
    uint4* dstrow = reinterpret_cast<uint4*>(q2t + ((size_t)b * 2048 + n0 + nl) * 128);
#pragma unroll
    for (int j = 0; j < 4; ++j)
        dstrow[(seg * 4 + j) ^ sw] = *reinterpret_cast<const uint4*>(&lds[nl][seg * 32 + j * 8]);
}

// ---------------- fused GEMM: one block per (b, mt) 128x2048 row-panel. NO LDS staging;
// rolling B registers (loads older than stores — R16, best=191.5us).
// NEW (R21): sweep-2 processes tile PAIRS: quantize into int8-PACKED registers (exact),
// then a store-only phase of 32 back-to-back f32x4 stores with only VALU unpack between
// (VALU doesn't touch vmcnt) -> 2x outstanding store bytes, fill-kernel-like bursts. ----------------
__global__ __launch_bounds__(256, 2) void gemm_fused(const unsigned short* __restrict__ qa,
                                                     const unsigned short* __restrict__ qbt,
                                                     const float* __restrict__ s1,
                                                     float* __restrict__ out) {
    int id = blockIdx.x;
    int nid = (id & 7) * 64 + (id >> 3);           // batch-grouped XCD mapping (512 % 8 == 0)
    int b = nid >> 4, mt = nid & 15;

    __shared__ float rowAmax[128], sOsc[128], sQs[128], sS1[128];

    int tid = threadIdx.x, wave = tid >> 6, lane = tid & 63;
    if (tid < 128) {
        rowAmax[tid] = 0.f;
        sS1[tid] = s1[b * 2048 + mt * 128 + tid];
    }

    int wm = wave >> 1, wn = wave & 1;             // 2x2 waves, 64x64 output each
    int lr = lane & 15, lg = lane >> 4;
    int swz = (lr & 7) << 3;                       // XOR swizzle baked into the images

    // A fragments: direct global -> registers (32 KB/block, L2/L3-hot)
    bf16x8 afr[4][4];
    {
        const unsigned short* Ai = qa + (size_t)(b * 16 + mt) * 16384;
#pragma unroll
        for (int ks = 0; ks < 4; ++ks)
#pragma unroll
            for (int mi = 0; mi < 4; ++mi)
                afr[ks][mi] = *reinterpret_cast<const bf16x8*>(
                    &Ai[(wm * 64 + mi * 16 + lr) * 128 + ((ks * 32 + lg * 8) ^ swz)]);
    }

    const unsigned short* Bimg = qbt + (size_t)b * 16 * 16384;
    auto boff = [&](int nt, int ks, int ni) -> size_t {
        return (size_t)(nt * 128 + wn * 64 + ni * 16 + lr) * 128 + ((ks * 32 + lg * 8) ^ swz);
    };

    // rolling B fragment registers: preload tile 0
    bf16x8 bfr[4][4];
#pragma unroll
    for (int ks = 0; ks < 4; ++ks)
#pragma unroll
        for (int ni = 0; ni < 4; ++ni)
            bfr[ks][ni] = *reinterpret_cast<const bf16x8*>(&Bimg[boff(0, ks, ni)]);

    size_t ob = (size_t)b * 2048 * 2048;
    float rmax[4] = {0.f, 0.f, 0.f, 0.f};          // per-lane running |C| max, one per mi

    // ================= sweep 1: amax (no barriers, rolling refill) — R16 verbatim =================
    for (int nt = 0; nt < 16; ++nt) {
        int nn = (nt + 1) & 15;                    // nt=15 reloads tile 0 for sweep 2
        f32x4 acc[4][4];
#pragma unroll
        for (int mi = 0; mi < 4; ++mi)
#pragma unroll
            for (int ni = 0; ni < 4; ++ni) {
                f32x4 z = {0.f, 0.f, 0.f, 0.f};
                acc[mi][ni] = z;
            }
#pragma unroll
        for (int ks = 0; ks < 4; ++ks) {
            // SWAPPED operands (R10/R12-verified): lane row=lr, cols=lg*4+r per ni
#pragma unroll
            for (int mi = 0; mi < 4; ++mi)
#pragma unroll
                for (int ni = 0; ni < 4; ++ni)
                    acc[mi][ni] = __builtin_amdgcn_mfma_f32_16x16x32_bf16(bfr[ks][ni], afr[ks][mi], acc[mi][ni], 0, 0, 0);
            // refill bfr[ks] with next tile right after last use (loads precede any stores)
#pragma unroll
            for (int ni = 0; ni < 4; ++ni)
                bfr[ks][ni] = *reinterpret_cast<const bf16x8*>(&Bimg[boff(nn, ks, ni)]);
        }
#pragma unroll
        for (int mi = 0; mi < 4; ++mi)
#pragma unroll
            for (int ni = 0; ni < 4; ++ni)
#pragma unroll
                for (int r = 0; r < 4; ++r)
                    rmax[mi] = fmaxf(rmax[mi], fabsf(acc[mi][ni][r]));
    }

    // ================= boundary: reduce amax -> per-row osc =================
#pragma unroll
    for (int mi = 0; mi < 4; ++mi) {
        float v = rmax[mi];
        v = fmaxf(v, __shfl_xor(v, 16));
        v = fmaxf(v, __shfl_xor(v, 32));
        if (lg == 0) {                             // raw amax >=0: uint compare == float compare
            int row = wm * 64 + mi * 16 + lr;
            atomicMax(reinterpret_cast<unsigned*>(&rowAmax[row]), __float_as_uint(v));
        }
    }
    __syncthreads();
    if (tid < 128) {
        float am = rowAmax[tid] * sS1[tid];
        float osc = fmaxf(am, EPSQ) / QMAXF;
        sOsc[tid] = osc;
        sQs[tid] = sS1[tid] / osc;                 // folded (raw_acc * s1) / osc
    }
    __syncthreads();                               // bfr holds tile 0 again (rolled at nt=15)

    // per-lane row constants (row = wm*64+mi*16+lr fixed per lane)
    float qsr[4], oscr[4];
#pragma unroll
    for (int mi = 0; mi < 4; ++mi) {
        int row = wm * 64 + mi * 16 + lr;
        qsr[mi] = sQs[row];
        oscr[mi] = sOsc[row];
    }

    // ================= sweep 2: tile pairs — compute+pack, then store-only burst =================
    for (int g = 0; g < 8; ++g) {
        unsigned pk[2][4][4];                      // int8-packed outputs (constant indices only)
#pragma unroll
        for (int j = 0; j < 2; ++j) {
            int nt = g * 2 + j;
            int nn = (nt + 1) & 15;
            f32x4 acc[4][4];
#pragma unroll
            for (int mi = 0; mi < 4; ++mi)
#pragma unroll
                for (int ni = 0; ni < 4; ++ni) {
                    f32x4 z = {0.f, 0.f, 0.f, 0.f};
                    acc[mi][ni] = z;
                }
#pragma unroll
            for (int ks = 0; ks < 4; ++ks) {
#pragma unroll
                for (int mi = 0; mi < 4; ++mi)
#pragma unroll
                    for (int ni = 0; ni < 4; ++ni)
                        acc[mi][ni] = __builtin_amdgcn_mfma_f32_16x16x32_bf16(bfr[ks][ni], afr[ks][mi], acc[mi][ni], 0, 0, 0);
#pragma unroll
                for (int ni = 0; ni < 4; ++ni)
                    bfr[ks][ni] = *reinterpret_cast<const bf16x8*>(&Bimg[boff(nn, ks, ni)]);
            }
            // quantize -> exact int8 pack (values are integers in [-128,127])
#pragma unroll
            for (int mi = 0; mi < 4; ++mi) {
                float qs = qsr[mi];
#pragma unroll
                for (int ni = 0; ni < 4; ++ni) {
                    int i0 = (int)fminf(fmaxf(rintf(acc[mi][ni][0] * qs), -128.f), 127.f);
                    int i1 = (int)fminf(fmaxf(rintf(acc[mi][ni][1] * qs), -128.f), 127.f);
                    int i2 = (int)fminf(fmaxf(rintf(acc[mi][ni][2] * qs), -128.f), 127.f);
                    int i3 = (int)fminf(fmaxf(rintf(acc[mi][ni][3] * qs), -128.f), 127.f);
                    pk[j][mi][ni] = (unsigned)(i0 & 255) | ((unsigned)(i1 & 255) << 8) |
                                    ((unsigned)(i2 & 255) << 16) | ((unsigned)(i3 & 255) << 24);
                }
            }
        }
        // ---- store-only phase: 32 f32x4 stores, only VALU (unpack) between them ----
#pragma unroll
        for (int j = 0; j < 2; ++j) {
            int nt = g * 2 + j;
#pragma unroll
            for (int mi = 0; mi < 4; ++mi) {
                int row = wm * 64 + mi * 16 + lr;
                float osc = oscr[mi];
                size_t rowoff = ob + (size_t)(mt * 128 + row) * 2048 + nt * 128 + wn * 64 + lg * 4;
#pragma unroll
                for (int ni = 0; ni < 4; ++ni) {
                    unsigned p = pk[j][mi][ni];
                    f32x4 qv;
                    qv[0] = (float)((int)(p << 24) >> 24) * osc;
                    qv[1] = (float)((int)(p << 16) >> 24) * osc;
                    qv[2] = (float)((int)(p << 8) >> 24) * osc;
                    qv[3] = (float)((int)p >> 24) * osc;
                    *reinterpret_cast<f32x4*>(&out[rowoff + ni * 16]) = qv;
                }
            }
        }
    }
}

extern "C" void kernel_launch(void* const* d_in, const int* in_sizes, int n_in,
                              void* d_out, int out_size, void* d_ws, size_t ws_size,
                              hipStream_t stream) {
    const float* in1 = (const float*)d_in[0];  // [2,16,2048,128]
    const float* in2 = (const float*)d_in[1];  // [2,16,128,2048]
    char* ws = (char*)d_ws;
    unsigned short* q1  = (unsigned short*)(ws + OFF_Q1);
    unsigned short* q2t = (unsigned short*)(ws + OFF_Q2T);
    float* s1   = (float*)(ws + OFF_S1);
    float* s2   = (float*)(ws + OFF_S2);
    float* out  = (float*)d_out;

    quant_rows128 <<<BB * MM / 4, 256, 0, stream>>>(in1, q1, s1);
    amax_rows2048 <<<BB * KK,     256, 0, stream>>>(in2, s2);
    quant_transpose<<<BB * (NN / 64), 256, 0, stream>>>(in2, s2, q2t);
    gemm_fused    <<<BB * 16,     256, 0, stream>>>(q1, q2t, s1, out);
}